// Round 4
// baseline (1919.575 us; speedup 1.0000x reference)
//
#include <hip/hip_runtime.h>
#include <hip/hip_bf16.h>
#include <cstddef>

#define N_NODES 30000
#define N_EDGES 100000
#define N_TYPES 6
#define D_IN 128
#define HC 256
#define NH 8
#define CH 32

typedef __attribute__((ext_vector_type(8))) unsigned short ushort8_t;
typedef __attribute__((ext_vector_type(4))) unsigned short ushort4_t;
typedef __attribute__((ext_vector_type(8))) __bf16 bf16x8;
typedef __attribute__((ext_vector_type(4))) float floatx4;

__device__ inline unsigned short f2bf(float f) {
    unsigned u = __float_as_uint(f);
    u += 0x7fffu + ((u >> 16) & 1u);
    return (unsigned short)(u >> 16);
}
__device__ inline float bf2f(unsigned short u) {
    return __uint_as_float(((unsigned)u) << 16);
}

// ---------------- fills / converts ----------------
__global__ void zero4(float4* __restrict__ p, int n4) {
    int g = blockIdx.x * blockDim.x + threadIdx.x;
    if (g < n4) p[g] = make_float4(0.f, 0.f, 0.f, 0.f);
}
__global__ void zero_i(int* __restrict__ p, int n) {
    int g = blockIdx.x * blockDim.x + threadIdx.x;
    if (g < n) p[g] = 0;
}
__global__ void to_bf16(const float* __restrict__ x, unsigned short* __restrict__ o, int n4) {
    int g = blockIdx.x * blockDim.x + threadIdx.x;
    if (g >= n4) return;
    float4 v = ((const float4*)x)[g];
    ushort4_t p;
    p[0] = f2bf(v.x); p[1] = f2bf(v.y); p[2] = f2bf(v.z); p[3] = f2bf(v.w);
    *(ushort4_t*)&o[(size_t)g * 4] = p;
}

// ---------------- batched CSR build (all 6 types) ----------------
__global__ void hist_all(const int* __restrict__ ei, int* __restrict__ counts) {
    int t = blockIdx.y;
    int e = blockIdx.x * 256 + threadIdx.x;
    if (e < N_EDGES)
        atomicAdd(&counts[t * N_NODES + ei[(size_t)t * 2 * N_EDGES + N_EDGES + e]], 1);
}

#define SCAN_T 1024
#define SCAN_C 30
__global__ __launch_bounds__(1024) void scan_all(const int* __restrict__ counts_g,
                                                 int* __restrict__ row_ptr_g,
                                                 int* __restrict__ cursor_g) {
    int t = blockIdx.x;
    const int* counts = counts_g + t * N_NODES;
    int* row_ptr = row_ptr_g + t * (N_NODES + 1);
    int* cursor = cursor_g + t * N_NODES;
    __shared__ int part[SCAN_T];
    int tid = threadIdx.x;
    int base = tid * SCAN_C;
    int loc[SCAN_C];
    int s = 0;
    #pragma unroll
    for (int i = 0; i < SCAN_C; ++i) {
        int idx = base + i;
        int v = (idx < N_NODES) ? counts[idx] : 0;
        loc[i] = s; s += v;
    }
    part[tid] = s;
    __syncthreads();
    int tot = s;
    for (int d = 1; d < SCAN_T; d <<= 1) {
        int v = (tid >= d) ? part[tid - d] : 0;
        __syncthreads();
        part[tid] += v;
        __syncthreads();
    }
    int off = part[tid] - tot;
    #pragma unroll
    for (int i = 0; i < SCAN_C; ++i) {
        int idx = base + i;
        if (idx < N_NODES) { int r = off + loc[i]; row_ptr[idx] = r; cursor[idx] = r; }
    }
    if (tid == SCAN_T - 1) row_ptr[N_NODES] = part[SCAN_T - 1];
}

__global__ void fill_all(const int* __restrict__ ei, int* __restrict__ cursor,
                         int* __restrict__ elist) {
    int t = blockIdx.y;
    int e = blockIdx.x * 256 + threadIdx.x;
    if (e < N_EDGES) {
        const int* src = ei + (size_t)t * 2 * N_EDGES;
        const int* dst = src + N_EDGES;
        int pos = atomicAdd(&cursor[t * N_NODES + dst[e]], 1);
        elist[t * N_EDGES + pos] = src[e];
    }
}

// ---------------- attention dst-weight precompute ----------------
__global__ void att_weight_all(const float* __restrict__ W1d, const float* __restrict__ a1d,
                               const float* __restrict__ W2d, const float* __restrict__ a2d,
                               float* __restrict__ wd1, float* __restrict__ wd2) {
    int g = blockIdx.x * blockDim.x + threadIdx.x;
    const int per_t = (D_IN + HC) * NH;
    if (g >= N_TYPES * per_t) return;
    int t = g / per_t, r = g % per_t;
    if (r < D_IN * NH) {
        int k = r >> 3, h = r & 7;
        const float* wr = W1d + (size_t)t * D_IN * HC + (size_t)k * HC + h * CH;
        const float* ar = a1d + t * HC + h * CH;
        float s = 0.f;
        #pragma unroll
        for (int c = 0; c < CH; ++c) s += wr[c] * ar[c];
        wd1[t * D_IN * NH + r] = s;
    } else {
        r -= D_IN * NH;
        int k = r >> 3, h = r & 7;
        const float* wr = W2d + (size_t)t * HC * HC + (size_t)k * HC + h * CH;
        const float* ar = a2d + t * HC + h * CH;
        float s = 0.f;
        #pragma unroll
        for (int c = 0; c < CH; ++c) s += wr[c] * ar[c];
        wd2[t * HC * NH + r] = s;
    }
}

// ---------------- MFMA bf16 GEMM (bf16 A in, bf16 C out) + fused att logits ----------------
__global__ __launch_bounds__(256) void gemm_att(const unsigned short* __restrict__ A,
                                                const float* __restrict__ B,
                                                unsigned short* __restrict__ Cp,
                                                const float* __restrict__ att,
                                                float* __restrict__ e_out,
                                                int M, int K, int N) {
    __shared__ unsigned short As[64 * 40];
    __shared__ unsigned short Bs[64 * 40];

    const int tid = threadIdx.x;
    const int w = tid >> 6;
    const int lane = tid & 63;
    const int col = lane & 15;
    const int quad = lane >> 4;
    const int m0 = blockIdx.x * 64;
    const int n0 = blockIdx.y * 64;

    const int am = tid >> 2;
    const int ak = (tid & 3) * 8;
    const int bk2 = (tid >> 4) * 2;
    const int bn4 = (tid & 15) * 4;

    floatx4 acc[4];
    #pragma unroll
    for (int ct = 0; ct < 4; ++ct) acc[ct] = (floatx4){0.f, 0.f, 0.f, 0.f};

    for (int k0 = 0; k0 < K; k0 += 32) {
        {
            int gm = m0 + am;
            ushort8_t v = (ushort8_t){0, 0, 0, 0, 0, 0, 0, 0};
            if (gm < M) v = *(const ushort8_t*)&A[(size_t)gm * K + k0 + ak];
            *(ushort8_t*)&As[am * 40 + ak] = v;
        }
        {
            const float4 r0 = *(const float4*)&B[(size_t)(k0 + bk2) * N + n0 + bn4];
            const float4 r1 = *(const float4*)&B[(size_t)(k0 + bk2 + 1) * N + n0 + bn4];
            float a0[4] = {r0.x, r0.y, r0.z, r0.w};
            float a1[4] = {r1.x, r1.y, r1.z, r1.w};
            #pragma unroll
            for (int j = 0; j < 4; ++j) {
                unsigned pk = (unsigned)f2bf(a0[j]) | ((unsigned)f2bf(a1[j]) << 16);
                *(unsigned*)&Bs[(bn4 + j) * 40 + bk2] = pk;
            }
        }
        __syncthreads();
        {
            ushort8_t araw = *(const ushort8_t*)&As[(w * 16 + col) * 40 + quad * 8];
            bf16x8 af = __builtin_bit_cast(bf16x8, araw);
            #pragma unroll
            for (int ct = 0; ct < 4; ++ct) {
                ushort8_t braw = *(const ushort8_t*)&Bs[(ct * 16 + col) * 40 + quad * 8];
                bf16x8 bf = __builtin_bit_cast(bf16x8, braw);
                acc[ct] = __builtin_amdgcn_mfma_f32_16x16x32_bf16(af, bf, acc[ct], 0, 0, 0);
            }
        }
        __syncthreads();
    }

    #pragma unroll
    for (int ct = 0; ct < 4; ++ct) {
        #pragma unroll
        for (int r = 0; r < 4; ++r) {
            int gm = m0 + w * 16 + quad * 4 + r;
            if (gm < M) Cp[(size_t)gm * N + n0 + ct * 16 + col] = f2bf(acc[ct][r]);
        }
    }

    float attv[4];
    #pragma unroll
    for (int ct = 0; ct < 4; ++ct) attv[ct] = att[n0 + ct * 16 + col];
    const int hbase = n0 >> 5;
    #pragma unroll
    for (int r = 0; r < 4; ++r) {
        float h0v = acc[0][r] * attv[0] + acc[1][r] * attv[1];
        float h1v = acc[2][r] * attv[2] + acc[3][r] * attv[3];
        #pragma unroll
        for (int off = 1; off < 16; off <<= 1) {
            h0v += __shfl_xor(h0v, off);
            h1v += __shfl_xor(h1v, off);
        }
        if (col == 0) {
            int gm = m0 + w * 16 + quad * 4 + r;
            if (gm < M) {
                e_out[gm * NH + hbase] = h0v;
                e_out[gm * NH + hbase + 1] = h1v;
            }
        }
    }
}

// ---------------- layer-1 gather: single-pass softmax-agg + LN + ed2 compute ----------------
__global__ __launch_bounds__(256) void gather_l1(const int* __restrict__ row_ptr,
                                                 const int* __restrict__ elist,
                                                 const float* __restrict__ es,
                                                 const float* __restrict__ xd,
                                                 const float* __restrict__ w1,
                                                 const unsigned short* __restrict__ hs,
                                                 const float* __restrict__ bias,
                                                 const float* __restrict__ gam,
                                                 const float* __restrict__ bet,
                                                 const float* __restrict__ w2,
                                                 float* __restrict__ ed2g) {
    const int lane = threadIdx.x & 63;
    const int d = blockIdx.x * 4 + (threadIdx.x >> 6);

    // ed1[h] = x_tgt[d,:] @ w1
    float e1v[8];
    #pragma unroll
    for (int h = 0; h < 8; ++h) e1v[h] = 0.f;
    #pragma unroll
    for (int rep = 0; rep < 2; ++rep) {
        int k = rep * 64 + lane;
        float xv = xd[(size_t)d * D_IN + k];
        const float* wr = w1 + k * 8;
        #pragma unroll
        for (int h = 0; h < 8; ++h) e1v[h] += xv * wr[h];
    }
    #pragma unroll
    for (int off = 1; off < 64; off <<= 1)
        #pragma unroll
        for (int h = 0; h < 8; ++h) e1v[h] += __shfl_xor(e1v[h], off);

    const int h_l = lane >> 3;
    const float ed_mine = e1v[h_l];
    const int e0 = row_ptr[d], e1n = row_ptr[d + 1];

    float den = 0.f;
    float4 acc = make_float4(0.f, 0.f, 0.f, 0.f);
    for (int i = e0; i < e1n; ++i) {
        int s = elist[i];
        float x = es[s * NH + h_l] + ed_mine;
        x = (x >= 0.f) ? x : 0.2f * x;
        float ex = __expf(x);
        den += ex;
        ushort4_t hv = *(const ushort4_t*)&hs[(size_t)s * HC + lane * 4];
        acc.x += ex * bf2f(hv[0]); acc.y += ex * bf2f(hv[1]);
        acc.z += ex * bf2f(hv[2]); acc.w += ex * bf2f(hv[3]);
    }
    float inv = 1.f / (den + 1e-16f);
    float4 bv = *(const float4*)&bias[lane * 4];
    acc.x = acc.x * inv + bv.x; acc.y = acc.y * inv + bv.y;
    acc.z = acc.z * inv + bv.z; acc.w = acc.w * inv + bv.w;

    // LN + ReLU
    float s1 = acc.x + acc.y + acc.z + acc.w;
    float s2 = acc.x * acc.x + acc.y * acc.y + acc.z * acc.z + acc.w * acc.w;
    #pragma unroll
    for (int off = 1; off < 64; off <<= 1) { s1 += __shfl_xor(s1, off); s2 += __shfl_xor(s2, off); }
    float mu = s1 * (1.f / 256.f);
    float var = s2 * (1.f / 256.f) - mu * mu;
    float rstd = rsqrtf(var + 1e-5f);
    float4 g4 = *(const float4*)&gam[lane * 4];
    float4 b4 = *(const float4*)&bet[lane * 4];
    float ya[4];
    ya[0] = fmaxf((acc.x - mu) * rstd * g4.x + b4.x, 0.f);
    ya[1] = fmaxf((acc.y - mu) * rstd * g4.y + b4.y, 0.f);
    ya[2] = fmaxf((acc.z - mu) * rstd * g4.z + b4.z, 0.f);
    ya[3] = fmaxf((acc.w - mu) * rstd * g4.w + b4.w, 0.f);

    // ed2[h] = y @ w2 (y = x1[d,:], never materialized)
    float e2v[8];
    #pragma unroll
    for (int h = 0; h < 8; ++h) e2v[h] = 0.f;
    #pragma unroll
    for (int j = 0; j < 4; ++j) {
        int c = lane * 4 + j;
        const float* wr = w2 + c * 8;
        #pragma unroll
        for (int h = 0; h < 8; ++h) e2v[h] += ya[j] * wr[h];
    }
    #pragma unroll
    for (int off = 1; off < 64; off <<= 1)
        #pragma unroll
        for (int h = 0; h < 8; ++h) e2v[h] += __shfl_xor(e2v[h], off);
    if (lane < 8) ed2g[d * NH + lane] = e2v[lane];
}

// ---------------- layer-2 gather: single-pass agg + LN + fused pooling ----------------
__global__ __launch_bounds__(256) void gather_l2(const int* __restrict__ row_ptr,
                                                 const int* __restrict__ elist,
                                                 const float* __restrict__ es,
                                                 const float* __restrict__ ed2g,
                                                 const unsigned short* __restrict__ hs,
                                                 const float* __restrict__ bias,
                                                 const float* __restrict__ gam,
                                                 const float* __restrict__ bet,
                                                 float* __restrict__ deng,
                                                 float* __restrict__ psum) {
    __shared__ float sacc[4][260];
    const int tid = threadIdx.x;
    const int lane = tid & 63;
    const int w = tid >> 6;
    const int d = blockIdx.x * 4 + w;
    const int h_l = lane >> 3;

    const float ed_mine = ed2g[d * NH + h_l];
    const int e0 = row_ptr[d], e1n = row_ptr[d + 1];

    float den = 0.f;
    float4 acc = make_float4(0.f, 0.f, 0.f, 0.f);
    for (int i = e0; i < e1n; ++i) {
        int s = elist[i];
        float x = es[s * NH + h_l] + ed_mine;
        x = (x >= 0.f) ? x : 0.2f * x;
        float ex = __expf(x);
        den += ex;
        ushort4_t hv = *(const ushort4_t*)&hs[(size_t)s * HC + lane * 4];
        acc.x += ex * bf2f(hv[0]); acc.y += ex * bf2f(hv[1]);
        acc.z += ex * bf2f(hv[2]); acc.w += ex * bf2f(hv[3]);
    }
    if ((lane & 7) == 0) deng[d * NH + h_l] = den;
    float inv = 1.f / (den + 1e-16f);
    float4 bv = *(const float4*)&bias[lane * 4];
    acc.x = acc.x * inv + bv.x; acc.y = acc.y * inv + bv.y;
    acc.z = acc.z * inv + bv.z; acc.w = acc.w * inv + bv.w;

    float s1 = acc.x + acc.y + acc.z + acc.w;
    float s2 = acc.x * acc.x + acc.y * acc.y + acc.z * acc.z + acc.w * acc.w;
    #pragma unroll
    for (int off = 1; off < 64; off <<= 1) { s1 += __shfl_xor(s1, off); s2 += __shfl_xor(s2, off); }
    float mu = s1 * (1.f / 256.f);
    float var = s2 * (1.f / 256.f) - mu * mu;
    float rstd = rsqrtf(var + 1e-5f);
    float4 g4 = *(const float4*)&gam[lane * 4];
    float4 b4 = *(const float4*)&bet[lane * 4];
    float4 y;
    y.x = fmaxf((acc.x - mu) * rstd * g4.x + b4.x, 0.f);
    y.y = fmaxf((acc.y - mu) * rstd * g4.y + b4.y, 0.f);
    y.z = fmaxf((acc.z - mu) * rstd * g4.z + b4.z, 0.f);
    y.w = fmaxf((acc.w - mu) * rstd * g4.w + b4.w, 0.f);

    *(float4*)&sacc[w][lane * 4] = y;
    __syncthreads();
    float tot = sacc[0][tid] + sacc[1][tid] + sacc[2][tid] + sacc[3][tid];
    atomicAdd(&psum[tid], tot);
}

// ---------------- flat alpha2 writer ----------------
__global__ void alpha_k(const int* __restrict__ src, const int* __restrict__ dst,
                        const float* __restrict__ es, const float* __restrict__ ed2g,
                        const float* __restrict__ deng, float* __restrict__ out) {
    int g = blockIdx.x * blockDim.x + threadIdx.x;
    if (g >= N_EDGES * NH) return;
    int e = g >> 3, h = g & 7;
    int s = src[e], d = dst[e];
    float x = es[s * NH + h] + ed2g[d * NH + h];
    x = (x >= 0.f) ? x : 0.2f * x;
    out[g] = __expf(x) / (deng[d * NH + h] + 1e-16f);
}

// ---------------- x_pkg column sums ----------------
__global__ __launch_bounds__(256) void pkg_accum(const float* __restrict__ x, float* __restrict__ sums) {
    int tid = threadIdx.x;
    int col = tid & 127;
    int rof = tid >> 7;
    float acc = 0.f;
    for (int r = blockIdx.x * 2 + rof; r < N_NODES; r += gridDim.x * 2)
        acc += x[(size_t)r * D_IN + col];
    atomicAdd(&sums[col], acc);
}

// ---------------- final classifier dot ----------------
__global__ __launch_bounds__(256) void logits_k(const float* __restrict__ psums,
                                                const float* __restrict__ ksums,
                                                const float* __restrict__ Wc,
                                                const float* __restrict__ bc,
                                                float* __restrict__ out) {
    int tid = threadIdx.x;
    const float inv = 1.f / (float)N_NODES;
    float acc = 0.f;
    for (int i = tid; i < N_TYPES * HC; i += 256) acc += psums[i] * inv * Wc[i];
    if (tid < D_IN) acc += ksums[tid] * inv * Wc[N_TYPES * HC + tid];
    #pragma unroll
    for (int off = 32; off; off >>= 1) acc += __shfl_down(acc, off);
    __shared__ float w[4];
    if ((tid & 63) == 0) w[tid >> 6] = acc;
    __syncthreads();
    if (tid == 0) out[0] = w[0] + w[1] + w[2] + w[3] + bc[0];
}

static inline void zf(float* p, int n, hipStream_t stream) {
    int n4 = (n + 3) >> 2;
    zero4<<<(n4 + 255) / 256, 256, 0, stream>>>((float4*)p, n4);
}

extern "C" void kernel_launch(void* const* d_in, const int* in_sizes, int n_in,
                              void* d_out, int out_size, void* d_ws, size_t ws_size,
                              hipStream_t stream) {
    const float* x_pkg    = (const float*)d_in[0];
    const float* x_tgt    = (const float*)d_in[1];
    const int*   ei       = (const int*)d_in[2];
    const float* W1_src   = (const float*)d_in[3];
    const float* W1_dst   = (const float*)d_in[4];
    const float* att1_src = (const float*)d_in[5];
    const float* att1_dst = (const float*)d_in[6];
    const float* b1       = (const float*)d_in[7];
    const float* W2_src   = (const float*)d_in[8];
    const float* W2_dst   = (const float*)d_in[9];
    const float* att2_src = (const float*)d_in[10];
    const float* att2_dst = (const float*)d_in[11];
    const float* b2       = (const float*)d_in[12];
    const float* gamma    = (const float*)d_in[13];
    const float* beta     = (const float*)d_in[14];
    const float* Wc       = (const float*)d_in[15];
    const float* bc       = (const float*)d_in[16];
    float* out = (float*)d_out;

    // ---- workspace layout ----
    char* wsb = (char*)d_ws;
    unsigned short* xpkg_bf = (unsigned short*)wsb;                 // 30000*128
    unsigned short* hs_bf   = xpkg_bf + (size_t)N_NODES * D_IN;     // 30000*256
    float* es    = (float*)(hs_bf + (size_t)N_NODES * HC);          // 240000
    float* ed2g  = es + (size_t)N_NODES * NH;                       // 240000
    float* deng  = ed2g + (size_t)N_NODES * NH;                     // 240000
    float* psums = deng + (size_t)N_NODES * NH;                     // 1536
    float* ksums = psums + N_TYPES * HC;                            // 128
    float* wd1   = ksums + D_IN;                                    // 6*128*8
    float* wd2   = wd1 + N_TYPES * D_IN * NH;                       // 6*256*8
    int* counts  = (int*)(wd2 + N_TYPES * HC * NH);                 // 6*30000
    int* row_ptr = counts + N_TYPES * N_NODES;                      // 6*30001
    int* cursor  = row_ptr + N_TYPES * (N_NODES + 1);               // 6*30000
    int* elist   = cursor + N_TYPES * N_NODES;                      // 6*100000

    dim3 ggrid((N_NODES + 63) / 64, HC / 64);
    const int gth_blocks = N_NODES / 4;   // 7500, exact
    dim3 egrid((N_EDGES + 255) / 256, N_TYPES);

    zf(psums, N_TYPES * HC, stream);
    zf(ksums, D_IN, stream);
    pkg_accum<<<256, 256, 0, stream>>>(x_pkg, ksums);
    {
        int tot = N_TYPES * (D_IN + HC) * NH;
        att_weight_all<<<(tot + 255) / 256, 256, 0, stream>>>(W1_dst, att1_dst, W2_dst, att2_dst, wd1, wd2);
    }
    to_bf16<<<((N_NODES * D_IN / 4) + 255) / 256, 256, 0, stream>>>(x_pkg, xpkg_bf, N_NODES * D_IN / 4);
    zero_i<<<(N_TYPES * N_NODES + 255) / 256, 256, 0, stream>>>(counts, N_TYPES * N_NODES);
    hist_all<<<egrid, 256, 0, stream>>>(ei, counts);
    scan_all<<<N_TYPES, SCAN_T, 0, stream>>>(counts, row_ptr, cursor);
    fill_all<<<egrid, 256, 0, stream>>>(ei, cursor, elist);

    for (int t = 0; t < N_TYPES; ++t) {
        const int* src_t = ei + (size_t)t * 2 * N_EDGES;
        const int* dst_t = src_t + N_EDGES;
        const int* rp_t = row_ptr + t * (N_NODES + 1);
        const int* el_t = elist + t * N_EDGES;

        // ---- layer 1 ----
        gemm_att<<<ggrid, 256, 0, stream>>>(xpkg_bf, W1_src + (size_t)t * D_IN * HC, hs_bf,
                                            att1_src + t * HC, es, N_NODES, D_IN, HC);
        gather_l1<<<gth_blocks, 256, 0, stream>>>(rp_t, el_t, es,
                                                  x_tgt + (size_t)t * N_NODES * D_IN,
                                                  wd1 + t * D_IN * NH, hs_bf,
                                                  b1 + t * HC, gamma + t * HC, beta + t * HC,
                                                  wd2 + t * HC * NH, ed2g);

        // ---- layer 2 ----
        gemm_att<<<ggrid, 256, 0, stream>>>(xpkg_bf, W2_src + (size_t)t * D_IN * HC, hs_bf,
                                            att2_src + t * HC, es, N_NODES, D_IN, HC);
        gather_l2<<<gth_blocks, 256, 0, stream>>>(rp_t, el_t, es, ed2g, hs_bf,
                                                  b2 + t * HC, gamma + t * HC, beta + t * HC,
                                                  deng, psums + t * HC);
        alpha_k<<<(N_EDGES * NH + 255) / 256, 256, 0, stream>>>(src_t, dst_t, es, ed2g, deng,
                                                                out + 1 + (size_t)t * N_EDGES * NH);
    }

    logits_k<<<1, 256, 0, stream>>>(psums, ksums, Wc, bc, out);
}

// Round 5
// 1168.994 us; speedup vs baseline: 1.6421x; 1.6421x over previous
//
#include <hip/hip_runtime.h>
#include <hip/hip_bf16.h>
#include <cstddef>

#define N_NODES 30000
#define N_EDGES 100000
#define N_TYPES 6
#define D_IN 128
#define HC 256
#define NH 8
#define CH 32

typedef __attribute__((ext_vector_type(8))) unsigned short ushort8_t;
typedef __attribute__((ext_vector_type(4))) unsigned short ushort4_t;
typedef __attribute__((ext_vector_type(8))) __bf16 bf16x8;
typedef __attribute__((ext_vector_type(4))) float floatx4;

#define L2_NPB 32                         // dst nodes per gather_l2 block
#define L2_GRID ((N_NODES + L2_NPB - 1) / L2_NPB)   // 938

__device__ inline unsigned short f2bf(float f) {
    unsigned u = __float_as_uint(f);
    u += 0x7fffu + ((u >> 16) & 1u);
    return (unsigned short)(u >> 16);
}
__device__ inline float bf2f(unsigned short u) {
    return __uint_as_float(((unsigned)u) << 16);
}

// ---------------- fills / converts ----------------
__global__ void zero4(float4* __restrict__ p, int n4) {
    int g = blockIdx.x * blockDim.x + threadIdx.x;
    if (g < n4) p[g] = make_float4(0.f, 0.f, 0.f, 0.f);
}
__global__ void zero_i(int* __restrict__ p, int n) {
    int g = blockIdx.x * blockDim.x + threadIdx.x;
    if (g < n) p[g] = 0;
}
__global__ void to_bf16(const float* __restrict__ x, unsigned short* __restrict__ o, int n4) {
    int g = blockIdx.x * blockDim.x + threadIdx.x;
    if (g >= n4) return;
    float4 v = ((const float4*)x)[g];
    ushort4_t p;
    p[0] = f2bf(v.x); p[1] = f2bf(v.y); p[2] = f2bf(v.z); p[3] = f2bf(v.w);
    *(ushort4_t*)&o[(size_t)g * 4] = p;
}

// ---------------- batched CSR build (all 6 types) ----------------
__global__ void hist_all(const int* __restrict__ ei, int* __restrict__ counts) {
    int t = blockIdx.y;
    int e = blockIdx.x * 256 + threadIdx.x;
    if (e < N_EDGES)
        atomicAdd(&counts[t * N_NODES + ei[(size_t)t * 2 * N_EDGES + N_EDGES + e]], 1);
}

#define SCAN_T 1024
#define SCAN_C 30
__global__ __launch_bounds__(1024) void scan_all(const int* __restrict__ counts_g,
                                                 int* __restrict__ row_ptr_g,
                                                 int* __restrict__ cursor_g) {
    int t = blockIdx.x;
    const int* counts = counts_g + t * N_NODES;
    int* row_ptr = row_ptr_g + t * (N_NODES + 1);
    int* cursor = cursor_g + t * N_NODES;
    __shared__ int part[SCAN_T];
    int tid = threadIdx.x;
    int base = tid * SCAN_C;
    int loc[SCAN_C];
    int s = 0;
    #pragma unroll
    for (int i = 0; i < SCAN_C; ++i) {
        int idx = base + i;
        int v = (idx < N_NODES) ? counts[idx] : 0;
        loc[i] = s; s += v;
    }
    part[tid] = s;
    __syncthreads();
    int tot = s;
    for (int d = 1; d < SCAN_T; d <<= 1) {
        int v = (tid >= d) ? part[tid - d] : 0;
        __syncthreads();
        part[tid] += v;
        __syncthreads();
    }
    int off = part[tid] - tot;
    #pragma unroll
    for (int i = 0; i < SCAN_C; ++i) {
        int idx = base + i;
        if (idx < N_NODES) { int r = off + loc[i]; row_ptr[idx] = r; cursor[idx] = r; }
    }
    if (tid == SCAN_T - 1) row_ptr[N_NODES] = part[SCAN_T - 1];
}

__global__ void fill_all(const int* __restrict__ ei, int* __restrict__ cursor,
                         int* __restrict__ elist) {
    int t = blockIdx.y;
    int e = blockIdx.x * 256 + threadIdx.x;
    if (e < N_EDGES) {
        const int* src = ei + (size_t)t * 2 * N_EDGES;
        const int* dst = src + N_EDGES;
        int pos = atomicAdd(&cursor[t * N_NODES + dst[e]], 1);
        elist[t * N_EDGES + pos] = src[e];
    }
}

// ---------------- attention dst-weight precompute ----------------
__global__ void att_weight_all(const float* __restrict__ W1d, const float* __restrict__ a1d,
                               const float* __restrict__ W2d, const float* __restrict__ a2d,
                               float* __restrict__ wd1, float* __restrict__ wd2) {
    int g = blockIdx.x * blockDim.x + threadIdx.x;
    const int per_t = (D_IN + HC) * NH;
    if (g >= N_TYPES * per_t) return;
    int t = g / per_t, r = g % per_t;
    if (r < D_IN * NH) {
        int k = r >> 3, h = r & 7;
        const float* wr = W1d + (size_t)t * D_IN * HC + (size_t)k * HC + h * CH;
        const float* ar = a1d + t * HC + h * CH;
        float s = 0.f;
        #pragma unroll
        for (int c = 0; c < CH; ++c) s += wr[c] * ar[c];
        wd1[t * D_IN * NH + r] = s;
    } else {
        r -= D_IN * NH;
        int k = r >> 3, h = r & 7;
        const float* wr = W2d + (size_t)t * HC * HC + (size_t)k * HC + h * CH;
        const float* ar = a2d + t * HC + h * CH;
        float s = 0.f;
        #pragma unroll
        for (int c = 0; c < CH; ++c) s += wr[c] * ar[c];
        wd2[t * HC * NH + r] = s;
    }
}

// ---------------- MFMA bf16 GEMM (bf16 A in, bf16 C out) + fused att logits ----------------
__global__ __launch_bounds__(256) void gemm_att(const unsigned short* __restrict__ A,
                                                const float* __restrict__ B,
                                                unsigned short* __restrict__ Cp,
                                                const float* __restrict__ att,
                                                float* __restrict__ e_out,
                                                int M, int K, int N) {
    __shared__ unsigned short As[64 * 40];
    __shared__ unsigned short Bs[64 * 40];

    const int tid = threadIdx.x;
    const int w = tid >> 6;
    const int lane = tid & 63;
    const int col = lane & 15;
    const int quad = lane >> 4;
    const int m0 = blockIdx.x * 64;
    const int n0 = blockIdx.y * 64;

    const int am = tid >> 2;
    const int ak = (tid & 3) * 8;
    const int bk2 = (tid >> 4) * 2;
    const int bn4 = (tid & 15) * 4;

    floatx4 acc[4];
    #pragma unroll
    for (int ct = 0; ct < 4; ++ct) acc[ct] = (floatx4){0.f, 0.f, 0.f, 0.f};

    for (int k0 = 0; k0 < K; k0 += 32) {
        {
            int gm = m0 + am;
            ushort8_t v = (ushort8_t){0, 0, 0, 0, 0, 0, 0, 0};
            if (gm < M) v = *(const ushort8_t*)&A[(size_t)gm * K + k0 + ak];
            *(ushort8_t*)&As[am * 40 + ak] = v;
        }
        {
            const float4 r0 = *(const float4*)&B[(size_t)(k0 + bk2) * N + n0 + bn4];
            const float4 r1 = *(const float4*)&B[(size_t)(k0 + bk2 + 1) * N + n0 + bn4];
            float a0[4] = {r0.x, r0.y, r0.z, r0.w};
            float a1[4] = {r1.x, r1.y, r1.z, r1.w};
            #pragma unroll
            for (int j = 0; j < 4; ++j) {
                unsigned pk = (unsigned)f2bf(a0[j]) | ((unsigned)f2bf(a1[j]) << 16);
                *(unsigned*)&Bs[(bn4 + j) * 40 + bk2] = pk;
            }
        }
        __syncthreads();
        {
            ushort8_t araw = *(const ushort8_t*)&As[(w * 16 + col) * 40 + quad * 8];
            bf16x8 af = __builtin_bit_cast(bf16x8, araw);
            #pragma unroll
            for (int ct = 0; ct < 4; ++ct) {
                ushort8_t braw = *(const ushort8_t*)&Bs[(ct * 16 + col) * 40 + quad * 8];
                bf16x8 bf = __builtin_bit_cast(bf16x8, braw);
                acc[ct] = __builtin_amdgcn_mfma_f32_16x16x32_bf16(af, bf, acc[ct], 0, 0, 0);
            }
        }
        __syncthreads();
    }

    #pragma unroll
    for (int ct = 0; ct < 4; ++ct) {
        #pragma unroll
        for (int r = 0; r < 4; ++r) {
            int gm = m0 + w * 16 + quad * 4 + r;
            if (gm < M) Cp[(size_t)gm * N + n0 + ct * 16 + col] = f2bf(acc[ct][r]);
        }
    }

    float attv[4];
    #pragma unroll
    for (int ct = 0; ct < 4; ++ct) attv[ct] = att[n0 + ct * 16 + col];
    const int hbase = n0 >> 5;
    #pragma unroll
    for (int r = 0; r < 4; ++r) {
        float h0v = acc[0][r] * attv[0] + acc[1][r] * attv[1];
        float h1v = acc[2][r] * attv[2] + acc[3][r] * attv[3];
        #pragma unroll
        for (int off = 1; off < 16; off <<= 1) {
            h0v += __shfl_xor(h0v, off);
            h1v += __shfl_xor(h1v, off);
        }
        if (col == 0) {
            int gm = m0 + w * 16 + quad * 4 + r;
            if (gm < M) {
                e_out[gm * NH + hbase] = h0v;
                e_out[gm * NH + hbase + 1] = h1v;
            }
        }
    }
}

// ---------------- layer-1 gather: single-pass softmax-agg + LN + ed2 compute ----------------
__global__ __launch_bounds__(256) void gather_l1(const int* __restrict__ row_ptr,
                                                 const int* __restrict__ elist,
                                                 const float* __restrict__ es,
                                                 const float* __restrict__ xd,
                                                 const float* __restrict__ w1,
                                                 const unsigned short* __restrict__ hs,
                                                 const float* __restrict__ bias,
                                                 const float* __restrict__ gam,
                                                 const float* __restrict__ bet,
                                                 const float* __restrict__ w2,
                                                 float* __restrict__ ed2g) {
    const int lane = threadIdx.x & 63;
    const int d = blockIdx.x * 4 + (threadIdx.x >> 6);

    // ed1[h] = x_tgt[d,:] @ w1
    float e1v[8];
    #pragma unroll
    for (int h = 0; h < 8; ++h) e1v[h] = 0.f;
    #pragma unroll
    for (int rep = 0; rep < 2; ++rep) {
        int k = rep * 64 + lane;
        float xv = xd[(size_t)d * D_IN + k];
        const float* wr = w1 + k * 8;
        #pragma unroll
        for (int h = 0; h < 8; ++h) e1v[h] += xv * wr[h];
    }
    #pragma unroll
    for (int off = 1; off < 64; off <<= 1)
        #pragma unroll
        for (int h = 0; h < 8; ++h) e1v[h] += __shfl_xor(e1v[h], off);

    const int h_l = lane >> 3;
    const float ed_mine = e1v[h_l];
    const int e0 = row_ptr[d], e1n = row_ptr[d + 1];

    float den = 0.f;
    float4 acc = make_float4(0.f, 0.f, 0.f, 0.f);
    for (int i = e0; i < e1n; ++i) {
        int s = elist[i];
        float x = es[s * NH + h_l] + ed_mine;
        x = (x >= 0.f) ? x : 0.2f * x;
        float ex = __expf(x);
        den += ex;
        ushort4_t hv = *(const ushort4_t*)&hs[(size_t)s * HC + lane * 4];
        acc.x += ex * bf2f(hv[0]); acc.y += ex * bf2f(hv[1]);
        acc.z += ex * bf2f(hv[2]); acc.w += ex * bf2f(hv[3]);
    }
    float inv = 1.f / (den + 1e-16f);
    float4 bv = *(const float4*)&bias[lane * 4];
    acc.x = acc.x * inv + bv.x; acc.y = acc.y * inv + bv.y;
    acc.z = acc.z * inv + bv.z; acc.w = acc.w * inv + bv.w;

    // LN + ReLU
    float s1 = acc.x + acc.y + acc.z + acc.w;
    float s2 = acc.x * acc.x + acc.y * acc.y + acc.z * acc.z + acc.w * acc.w;
    #pragma unroll
    for (int off = 1; off < 64; off <<= 1) { s1 += __shfl_xor(s1, off); s2 += __shfl_xor(s2, off); }
    float mu = s1 * (1.f / 256.f);
    float var = s2 * (1.f / 256.f) - mu * mu;
    float rstd = rsqrtf(var + 1e-5f);
    float4 g4 = *(const float4*)&gam[lane * 4];
    float4 b4 = *(const float4*)&bet[lane * 4];
    float ya[4];
    ya[0] = fmaxf((acc.x - mu) * rstd * g4.x + b4.x, 0.f);
    ya[1] = fmaxf((acc.y - mu) * rstd * g4.y + b4.y, 0.f);
    ya[2] = fmaxf((acc.z - mu) * rstd * g4.z + b4.z, 0.f);
    ya[3] = fmaxf((acc.w - mu) * rstd * g4.w + b4.w, 0.f);

    // ed2[h] = y @ w2 (y = x1[d,:], never materialized)
    float e2v[8];
    #pragma unroll
    for (int h = 0; h < 8; ++h) e2v[h] = 0.f;
    #pragma unroll
    for (int j = 0; j < 4; ++j) {
        int c = lane * 4 + j;
        const float* wr = w2 + c * 8;
        #pragma unroll
        for (int h = 0; h < 8; ++h) e2v[h] += ya[j] * wr[h];
    }
    #pragma unroll
    for (int off = 1; off < 64; off <<= 1)
        #pragma unroll
        for (int h = 0; h < 8; ++h) e2v[h] += __shfl_xor(e2v[h], off);
    if (lane < 8) ed2g[d * NH + lane] = e2v[lane];
}

// ---------------- layer-2 gather: single-pass agg + LN; pooled partials -> plain store ----------------
__global__ __launch_bounds__(256) void gather_l2(const int* __restrict__ row_ptr,
                                                 const int* __restrict__ elist,
                                                 const float* __restrict__ es,
                                                 const float* __restrict__ ed2g,
                                                 const unsigned short* __restrict__ hs,
                                                 const float* __restrict__ bias,
                                                 const float* __restrict__ gam,
                                                 const float* __restrict__ bet,
                                                 float* __restrict__ deng,
                                                 float* __restrict__ psum_part) {
    const int tid = threadIdx.x;
    const int lane = tid & 63;
    const int w = tid >> 6;
    const int h_l = lane >> 3;
    const float4 bv = *(const float4*)&bias[lane * 4];
    const float4 g4 = *(const float4*)&gam[lane * 4];
    const float4 b4 = *(const float4*)&bet[lane * 4];

    float4 pool = make_float4(0.f, 0.f, 0.f, 0.f);
    const int base = blockIdx.x * L2_NPB;

    #pragma unroll 1
    for (int rep = 0; rep < L2_NPB / 4; ++rep) {
        const int d = base + rep * 4 + w;
        if (d >= N_NODES) break;

        const float ed_mine = ed2g[d * NH + h_l];
        const int e0 = row_ptr[d], e1n = row_ptr[d + 1];

        float den = 0.f;
        float4 acc = make_float4(0.f, 0.f, 0.f, 0.f);
        for (int i = e0; i < e1n; ++i) {
            int s = elist[i];
            float x = es[s * NH + h_l] + ed_mine;
            x = (x >= 0.f) ? x : 0.2f * x;
            float ex = __expf(x);
            den += ex;
            ushort4_t hv = *(const ushort4_t*)&hs[(size_t)s * HC + lane * 4];
            acc.x += ex * bf2f(hv[0]); acc.y += ex * bf2f(hv[1]);
            acc.z += ex * bf2f(hv[2]); acc.w += ex * bf2f(hv[3]);
        }
        if ((lane & 7) == 0) deng[d * NH + h_l] = den;
        float inv = 1.f / (den + 1e-16f);
        acc.x = acc.x * inv + bv.x; acc.y = acc.y * inv + bv.y;
        acc.z = acc.z * inv + bv.z; acc.w = acc.w * inv + bv.w;

        float s1 = acc.x + acc.y + acc.z + acc.w;
        float s2 = acc.x * acc.x + acc.y * acc.y + acc.z * acc.z + acc.w * acc.w;
        #pragma unroll
        for (int off = 1; off < 64; off <<= 1) { s1 += __shfl_xor(s1, off); s2 += __shfl_xor(s2, off); }
        float mu = s1 * (1.f / 256.f);
        float var = s2 * (1.f / 256.f) - mu * mu;
        float rstd = rsqrtf(var + 1e-5f);
        pool.x += fmaxf((acc.x - mu) * rstd * g4.x + b4.x, 0.f);
        pool.y += fmaxf((acc.y - mu) * rstd * g4.y + b4.y, 0.f);
        pool.z += fmaxf((acc.z - mu) * rstd * g4.z + b4.z, 0.f);
        pool.w += fmaxf((acc.w - mu) * rstd * g4.w + b4.w, 0.f);
    }

    __shared__ float sacc[4][260];
    *(float4*)&sacc[w][lane * 4] = pool;
    __syncthreads();
    float tot = sacc[0][tid] + sacc[1][tid] + sacc[2][tid] + sacc[3][tid];
    psum_part[(size_t)blockIdx.x * HC + tid] = tot;   // plain store, no atomics
}

// ---------------- reduce pooled partials (8 blocks -> 8 atomics/addr) ----------------
__global__ __launch_bounds__(256) void pool_reduce(const float* __restrict__ part,
                                                   float* __restrict__ psum) {
    int tid = threadIdx.x;
    float acc = 0.f;
    for (int b = blockIdx.x; b < L2_GRID; b += gridDim.x)
        acc += part[(size_t)b * HC + tid];
    atomicAdd(&psum[tid], acc);
}

// ---------------- flat alpha2 writer ----------------
__global__ void alpha_k(const int* __restrict__ src, const int* __restrict__ dst,
                        const float* __restrict__ es, const float* __restrict__ ed2g,
                        const float* __restrict__ deng, float* __restrict__ out) {
    int g = blockIdx.x * blockDim.x + threadIdx.x;
    if (g >= N_EDGES * NH) return;
    int e = g >> 3, h = g & 7;
    int s = src[e], d = dst[e];
    float x = es[s * NH + h] + ed2g[d * NH + h];
    x = (x >= 0.f) ? x : 0.2f * x;
    out[g] = __expf(x) / (deng[d * NH + h] + 1e-16f);
}

// ---------------- x_pkg column sums ----------------
__global__ __launch_bounds__(256) void pkg_accum(const float* __restrict__ x, float* __restrict__ sums) {
    int tid = threadIdx.x;
    int col = tid & 127;
    int rof = tid >> 7;
    float acc = 0.f;
    for (int r = blockIdx.x * 2 + rof; r < N_NODES; r += gridDim.x * 2)
        acc += x[(size_t)r * D_IN + col];
    atomicAdd(&sums[col], acc);
}

// ---------------- final classifier dot ----------------
__global__ __launch_bounds__(256) void logits_k(const float* __restrict__ psums,
                                                const float* __restrict__ ksums,
                                                const float* __restrict__ Wc,
                                                const float* __restrict__ bc,
                                                float* __restrict__ out) {
    int tid = threadIdx.x;
    const float inv = 1.f / (float)N_NODES;
    float acc = 0.f;
    for (int i = tid; i < N_TYPES * HC; i += 256) acc += psums[i] * inv * Wc[i];
    if (tid < D_IN) acc += ksums[tid] * inv * Wc[N_TYPES * HC + tid];
    #pragma unroll
    for (int off = 32; off; off >>= 1) acc += __shfl_down(acc, off);
    __shared__ float w[4];
    if ((tid & 63) == 0) w[tid >> 6] = acc;
    __syncthreads();
    if (tid == 0) out[0] = w[0] + w[1] + w[2] + w[3] + bc[0];
}

static inline void zf(float* p, int n, hipStream_t stream) {
    int n4 = (n + 3) >> 2;
    zero4<<<(n4 + 255) / 256, 256, 0, stream>>>((float4*)p, n4);
}

extern "C" void kernel_launch(void* const* d_in, const int* in_sizes, int n_in,
                              void* d_out, int out_size, void* d_ws, size_t ws_size,
                              hipStream_t stream) {
    const float* x_pkg    = (const float*)d_in[0];
    const float* x_tgt    = (const float*)d_in[1];
    const int*   ei       = (const int*)d_in[2];
    const float* W1_src   = (const float*)d_in[3];
    const float* W1_dst   = (const float*)d_in[4];
    const float* att1_src = (const float*)d_in[5];
    const float* att1_dst = (const float*)d_in[6];
    const float* b1       = (const float*)d_in[7];
    const float* W2_src   = (const float*)d_in[8];
    const float* W2_dst   = (const float*)d_in[9];
    const float* att2_src = (const float*)d_in[10];
    const float* att2_dst = (const float*)d_in[11];
    const float* b2       = (const float*)d_in[12];
    const float* gamma    = (const float*)d_in[13];
    const float* beta     = (const float*)d_in[14];
    const float* Wc       = (const float*)d_in[15];
    const float* bc       = (const float*)d_in[16];
    float* out = (float*)d_out;

    // ---- workspace layout ----
    char* wsb = (char*)d_ws;
    unsigned short* xpkg_bf = (unsigned short*)wsb;                 // 30000*128
    unsigned short* hs_bf   = xpkg_bf + (size_t)N_NODES * D_IN;     // 30000*256
    float* es    = (float*)(hs_bf + (size_t)N_NODES * HC);          // 240000
    float* ed2g  = es + (size_t)N_NODES * NH;                       // 240000
    float* deng  = ed2g + (size_t)N_NODES * NH;                     // 240000
    float* psums = deng + (size_t)N_NODES * NH;                     // 1536
    float* ksums = psums + N_TYPES * HC;                            // 128
    float* wd1   = ksums + D_IN;                                    // 6*128*8
    float* wd2   = wd1 + N_TYPES * D_IN * NH;                       // 6*256*8
    float* ppart = wd2 + N_TYPES * HC * NH;                         // L2_GRID*256
    int* counts  = (int*)(ppart + (size_t)L2_GRID * HC);            // 6*30000
    int* row_ptr = counts + N_TYPES * N_NODES;                      // 6*30001
    int* cursor  = row_ptr + N_TYPES * (N_NODES + 1);               // 6*30000
    int* elist   = cursor + N_TYPES * N_NODES;                      // 6*100000

    dim3 ggrid((N_NODES + 63) / 64, HC / 64);
    const int gth_blocks = N_NODES / 4;   // 7500, exact
    dim3 egrid((N_EDGES + 255) / 256, N_TYPES);

    zf(psums, N_TYPES * HC, stream);
    zf(ksums, D_IN, stream);
    pkg_accum<<<256, 256, 0, stream>>>(x_pkg, ksums);
    {
        int tot = N_TYPES * (D_IN + HC) * NH;
        att_weight_all<<<(tot + 255) / 256, 256, 0, stream>>>(W1_dst, att1_dst, W2_dst, att2_dst, wd1, wd2);
    }
    to_bf16<<<((N_NODES * D_IN / 4) + 255) / 256, 256, 0, stream>>>(x_pkg, xpkg_bf, N_NODES * D_IN / 4);
    zero_i<<<(N_TYPES * N_NODES + 255) / 256, 256, 0, stream>>>(counts, N_TYPES * N_NODES);
    hist_all<<<egrid, 256, 0, stream>>>(ei, counts);
    scan_all<<<N_TYPES, SCAN_T, 0, stream>>>(counts, row_ptr, cursor);
    fill_all<<<egrid, 256, 0, stream>>>(ei, cursor, elist);

    for (int t = 0; t < N_TYPES; ++t) {
        const int* src_t = ei + (size_t)t * 2 * N_EDGES;
        const int* dst_t = src_t + N_EDGES;
        const int* rp_t = row_ptr + t * (N_NODES + 1);
        const int* el_t = elist + t * N_EDGES;

        // ---- layer 1 ----
        gemm_att<<<ggrid, 256, 0, stream>>>(xpkg_bf, W1_src + (size_t)t * D_IN * HC, hs_bf,
                                            att1_src + t * HC, es, N_NODES, D_IN, HC);
        gather_l1<<<gth_blocks, 256, 0, stream>>>(rp_t, el_t, es,
                                                  x_tgt + (size_t)t * N_NODES * D_IN,
                                                  wd1 + t * D_IN * NH, hs_bf,
                                                  b1 + t * HC, gamma + t * HC, beta + t * HC,
                                                  wd2 + t * HC * NH, ed2g);

        // ---- layer 2 ----
        gemm_att<<<ggrid, 256, 0, stream>>>(xpkg_bf, W2_src + (size_t)t * D_IN * HC, hs_bf,
                                            att2_src + t * HC, es, N_NODES, D_IN, HC);
        gather_l2<<<L2_GRID, 256, 0, stream>>>(rp_t, el_t, es, ed2g, hs_bf,
                                               b2 + t * HC, gamma + t * HC, beta + t * HC,
                                               deng, ppart);
        pool_reduce<<<8, 256, 0, stream>>>(ppart, psums + t * HC);
        alpha_k<<<(N_EDGES * NH + 255) / 256, 256, 0, stream>>>(src_t, dst_t, es, ed2g, deng,
                                                                out + 1 + (size_t)t * N_EDGES * NH);
    }

    logits_k<<<1, 256, 0, stream>>>(psums, ksums, Wc, bc, out);
}

// Round 6
// 838.294 us; speedup vs baseline: 2.2899x; 1.3945x over previous
//
#include <hip/hip_runtime.h>
#include <hip/hip_bf16.h>
#include <cstddef>

#define N_NODES 30000
#define N_EDGES 100000
#define N_TYPES 6
#define D_IN 128
#define HC 256
#define NH 8
#define CH 32

typedef __attribute__((ext_vector_type(8))) unsigned short ushort8_t;
typedef __attribute__((ext_vector_type(4))) unsigned short ushort4_t;
typedef __attribute__((ext_vector_type(8))) __bf16 bf16x8;
typedef __attribute__((ext_vector_type(4))) float floatx4;

#define L2_NPB 32
#define L2_GRID ((N_NODES + L2_NPB - 1) / L2_NPB)   // 938

__device__ inline unsigned short f2bf(float f) {
    unsigned u = __float_as_uint(f);
    u += 0x7fffu + ((u >> 16) & 1u);
    return (unsigned short)(u >> 16);
}
__device__ inline float bf2f(unsigned short u) {
    return __uint_as_float(((unsigned)u) << 16);
}

// ---------------- fills / converts ----------------
__global__ void zero4(float4* __restrict__ p, int n4) {
    int g = blockIdx.x * blockDim.x + threadIdx.x;
    if (g < n4) p[g] = make_float4(0.f, 0.f, 0.f, 0.f);
}
__global__ void zero_i(int* __restrict__ p, int n) {
    int g = blockIdx.x * blockDim.x + threadIdx.x;
    if (g < n) p[g] = 0;
}
__global__ void to_bf16(const float* __restrict__ x, unsigned short* __restrict__ o, int n4) {
    int g = blockIdx.x * blockDim.x + threadIdx.x;
    if (g >= n4) return;
    float4 v = ((const float4*)x)[g];
    ushort4_t p;
    p[0] = f2bf(v.x); p[1] = f2bf(v.y); p[2] = f2bf(v.z); p[3] = f2bf(v.w);
    *(ushort4_t*)&o[(size_t)g * 4] = p;
}

// ---------------- batched CSR build (all 6 types) ----------------
__global__ void hist_all(const int* __restrict__ ei, int* __restrict__ counts) {
    int t = blockIdx.y;
    int e = blockIdx.x * 256 + threadIdx.x;
    if (e < N_EDGES)
        atomicAdd(&counts[t * N_NODES + ei[(size_t)t * 2 * N_EDGES + N_EDGES + e]], 1);
}

#define SCAN_T 1024
#define SCAN_C 30
__global__ __launch_bounds__(1024) void scan_all(const int* __restrict__ counts_g,
                                                 int* __restrict__ row_ptr_g,
                                                 int* __restrict__ cursor_g) {
    int t = blockIdx.x;
    const int* counts = counts_g + t * N_NODES;
    int* row_ptr = row_ptr_g + t * (N_NODES + 1);
    int* cursor = cursor_g + t * N_NODES;
    __shared__ int part[SCAN_T];
    int tid = threadIdx.x;
    int base = tid * SCAN_C;
    int loc[SCAN_C];
    int s = 0;
    #pragma unroll
    for (int i = 0; i < SCAN_C; ++i) {
        int idx = base + i;
        int v = (idx < N_NODES) ? counts[idx] : 0;
        loc[i] = s; s += v;
    }
    part[tid] = s;
    __syncthreads();
    int tot = s;
    for (int d = 1; d < SCAN_T; d <<= 1) {
        int v = (tid >= d) ? part[tid - d] : 0;
        __syncthreads();
        part[tid] += v;
        __syncthreads();
    }
    int off = part[tid] - tot;
    #pragma unroll
    for (int i = 0; i < SCAN_C; ++i) {
        int idx = base + i;
        if (idx < N_NODES) { int r = off + loc[i]; row_ptr[idx] = r; cursor[idx] = r; }
    }
    if (tid == SCAN_T - 1) row_ptr[N_NODES] = part[SCAN_T - 1];
}

__global__ void fill_all(const int* __restrict__ ei, int* __restrict__ cursor,
                         int* __restrict__ elist) {
    int t = blockIdx.y;
    int e = blockIdx.x * 256 + threadIdx.x;
    if (e < N_EDGES) {
        const int* src = ei + (size_t)t * 2 * N_EDGES;
        const int* dst = src + N_EDGES;
        int pos = atomicAdd(&cursor[t * N_NODES + dst[e]], 1);
        elist[t * N_EDGES + pos] = src[e];
    }
}

// ---------------- attention dst-weight precompute ----------------
__global__ void att_weight_all(const float* __restrict__ W1d, const float* __restrict__ a1d,
                               const float* __restrict__ W2d, const float* __restrict__ a2d,
                               float* __restrict__ wd1, float* __restrict__ wd2) {
    int g = blockIdx.x * blockDim.x + threadIdx.x;
    const int per_t = (D_IN + HC) * NH;
    if (g >= N_TYPES * per_t) return;
    int t = g / per_t, r = g % per_t;
    if (r < D_IN * NH) {
        int k = r >> 3, h = r & 7;
        const float* wr = W1d + (size_t)t * D_IN * HC + (size_t)k * HC + h * CH;
        const float* ar = a1d + t * HC + h * CH;
        float s = 0.f;
        #pragma unroll
        for (int c = 0; c < CH; ++c) s += wr[c] * ar[c];
        wd1[t * D_IN * NH + r] = s;
    } else {
        r -= D_IN * NH;
        int k = r >> 3, h = r & 7;
        const float* wr = W2d + (size_t)t * HC * HC + (size_t)k * HC + h * CH;
        const float* ar = a2d + t * HC + h * CH;
        float s = 0.f;
        #pragma unroll
        for (int c = 0; c < CH; ++c) s += wr[c] * ar[c];
        wd2[t * HC * NH + r] = s;
    }
}

// ---------------- ONE batched MFMA GEMM over 12 jobs (6x W1_src, 6x W2_src) ----------------
// A = xpkg_bf [30000,128] shared by all jobs. grid = (469, 4, 12).
__global__ __launch_bounds__(256) void gemm_all(const unsigned short* __restrict__ A,
                                                const float* __restrict__ W1s,
                                                const float* __restrict__ W2s,
                                                const float* __restrict__ att1,
                                                const float* __restrict__ att2,
                                                unsigned short* __restrict__ hs_all,
                                                float* __restrict__ es_all) {
    const int j = blockIdx.z;
    const float* B = (j < 6) ? W1s + (size_t)j * D_IN * HC
                             : W2s + (size_t)(j - 6) * D_IN * HC;
    const float* att = (j < 6) ? att1 + j * HC : att2 + (j - 6) * HC;
    unsigned short* Cp = hs_all + (size_t)j * N_NODES * HC;
    float* e_out = es_all + (size_t)j * N_NODES * NH;

    __shared__ unsigned short As[64 * 40];
    __shared__ unsigned short Bs[64 * 40];

    const int tid = threadIdx.x;
    const int w = tid >> 6;
    const int lane = tid & 63;
    const int col = lane & 15;
    const int quad = lane >> 4;
    const int m0 = blockIdx.x * 64;
    const int n0 = blockIdx.y * 64;

    const int am = tid >> 2;
    const int ak = (tid & 3) * 8;
    const int bk2 = (tid >> 4) * 2;
    const int bn4 = (tid & 15) * 4;

    floatx4 acc[4];
    #pragma unroll
    for (int ct = 0; ct < 4; ++ct) acc[ct] = (floatx4){0.f, 0.f, 0.f, 0.f};

    #pragma unroll
    for (int k0 = 0; k0 < D_IN; k0 += 32) {
        {
            int gm = m0 + am;
            ushort8_t v = (ushort8_t){0, 0, 0, 0, 0, 0, 0, 0};
            if (gm < N_NODES) v = *(const ushort8_t*)&A[(size_t)gm * D_IN + k0 + ak];
            *(ushort8_t*)&As[am * 40 + ak] = v;
        }
        {
            const float4 r0 = *(const float4*)&B[(size_t)(k0 + bk2) * HC + n0 + bn4];
            const float4 r1 = *(const float4*)&B[(size_t)(k0 + bk2 + 1) * HC + n0 + bn4];
            float a0[4] = {r0.x, r0.y, r0.z, r0.w};
            float a1[4] = {r1.x, r1.y, r1.z, r1.w};
            #pragma unroll
            for (int q = 0; q < 4; ++q) {
                unsigned pk = (unsigned)f2bf(a0[q]) | ((unsigned)f2bf(a1[q]) << 16);
                *(unsigned*)&Bs[(bn4 + q) * 40 + bk2] = pk;
            }
        }
        __syncthreads();
        {
            ushort8_t araw = *(const ushort8_t*)&As[(w * 16 + col) * 40 + quad * 8];
            bf16x8 af = __builtin_bit_cast(bf16x8, araw);
            #pragma unroll
            for (int ct = 0; ct < 4; ++ct) {
                ushort8_t braw = *(const ushort8_t*)&Bs[(ct * 16 + col) * 40 + quad * 8];
                bf16x8 bf = __builtin_bit_cast(bf16x8, braw);
                acc[ct] = __builtin_amdgcn_mfma_f32_16x16x32_bf16(af, bf, acc[ct], 0, 0, 0);
            }
        }
        __syncthreads();
    }

    #pragma unroll
    for (int ct = 0; ct < 4; ++ct) {
        #pragma unroll
        for (int r = 0; r < 4; ++r) {
            int gm = m0 + w * 16 + quad * 4 + r;
            if (gm < N_NODES) Cp[(size_t)gm * HC + n0 + ct * 16 + col] = f2bf(acc[ct][r]);
        }
    }

    float attv[4];
    #pragma unroll
    for (int ct = 0; ct < 4; ++ct) attv[ct] = att[n0 + ct * 16 + col];
    const int hbase = n0 >> 5;
    #pragma unroll
    for (int r = 0; r < 4; ++r) {
        float h0v = acc[0][r] * attv[0] + acc[1][r] * attv[1];
        float h1v = acc[2][r] * attv[2] + acc[3][r] * attv[3];
        #pragma unroll
        for (int off = 1; off < 16; off <<= 1) {
            h0v += __shfl_xor(h0v, off);
            h1v += __shfl_xor(h1v, off);
        }
        if (col == 0) {
            int gm = m0 + w * 16 + quad * 4 + r;
            if (gm < N_NODES) {
                e_out[gm * NH + hbase] = h0v;
                e_out[gm * NH + hbase + 1] = h1v;
            }
        }
    }
}

// ---------------- batched layer-1 gather (grid y = type) ----------------
__global__ __launch_bounds__(256) void gather_l1_all(const int* __restrict__ row_ptr_g,
                                                     const int* __restrict__ elist_g,
                                                     const float* __restrict__ es_all,
                                                     const float* __restrict__ x_tgt,
                                                     const float* __restrict__ wd1,
                                                     const unsigned short* __restrict__ hs_all,
                                                     const float* __restrict__ b1,
                                                     const float* __restrict__ gamma,
                                                     const float* __restrict__ beta,
                                                     const float* __restrict__ wd2,
                                                     float* __restrict__ ed2g_all) {
    const int t = blockIdx.y;
    const int* row_ptr = row_ptr_g + t * (N_NODES + 1);
    const int* elist = elist_g + t * N_EDGES;
    const float* es = es_all + (size_t)t * N_NODES * NH;
    const float* xd = x_tgt + (size_t)t * N_NODES * D_IN;
    const float* w1 = wd1 + t * D_IN * NH;
    const unsigned short* hs = hs_all + (size_t)t * N_NODES * HC;
    const float* bias = b1 + t * HC;
    const float* gam = gamma + t * HC;
    const float* bet = beta + t * HC;
    const float* w2 = wd2 + t * HC * NH;
    float* ed2g = ed2g_all + (size_t)t * N_NODES * NH;

    const int lane = threadIdx.x & 63;
    const int d = blockIdx.x * 4 + (threadIdx.x >> 6);

    float e1v[8];
    #pragma unroll
    for (int h = 0; h < 8; ++h) e1v[h] = 0.f;
    #pragma unroll
    for (int rep = 0; rep < 2; ++rep) {
        int k = rep * 64 + lane;
        float xv = xd[(size_t)d * D_IN + k];
        const float* wr = w1 + k * 8;
        #pragma unroll
        for (int h = 0; h < 8; ++h) e1v[h] += xv * wr[h];
    }
    #pragma unroll
    for (int off = 1; off < 64; off <<= 1)
        #pragma unroll
        for (int h = 0; h < 8; ++h) e1v[h] += __shfl_xor(e1v[h], off);

    const int h_l = lane >> 3;
    const float ed_mine = e1v[h_l];
    const int e0 = row_ptr[d], e1n = row_ptr[d + 1];

    float den = 0.f;
    float4 acc = make_float4(0.f, 0.f, 0.f, 0.f);
    for (int i = e0; i < e1n; ++i) {
        int s = elist[i];
        float x = es[s * NH + h_l] + ed_mine;
        x = (x >= 0.f) ? x : 0.2f * x;
        float ex = __expf(x);
        den += ex;
        ushort4_t hv = *(const ushort4_t*)&hs[(size_t)s * HC + lane * 4];
        acc.x += ex * bf2f(hv[0]); acc.y += ex * bf2f(hv[1]);
        acc.z += ex * bf2f(hv[2]); acc.w += ex * bf2f(hv[3]);
    }
    float inv = 1.f / (den + 1e-16f);
    float4 bv = *(const float4*)&bias[lane * 4];
    acc.x = acc.x * inv + bv.x; acc.y = acc.y * inv + bv.y;
    acc.z = acc.z * inv + bv.z; acc.w = acc.w * inv + bv.w;

    float s1 = acc.x + acc.y + acc.z + acc.w;
    float s2 = acc.x * acc.x + acc.y * acc.y + acc.z * acc.z + acc.w * acc.w;
    #pragma unroll
    for (int off = 1; off < 64; off <<= 1) { s1 += __shfl_xor(s1, off); s2 += __shfl_xor(s2, off); }
    float mu = s1 * (1.f / 256.f);
    float var = s2 * (1.f / 256.f) - mu * mu;
    float rstd = rsqrtf(var + 1e-5f);
    float4 g4 = *(const float4*)&gam[lane * 4];
    float4 b4 = *(const float4*)&bet[lane * 4];
    float ya[4];
    ya[0] = fmaxf((acc.x - mu) * rstd * g4.x + b4.x, 0.f);
    ya[1] = fmaxf((acc.y - mu) * rstd * g4.y + b4.y, 0.f);
    ya[2] = fmaxf((acc.z - mu) * rstd * g4.z + b4.z, 0.f);
    ya[3] = fmaxf((acc.w - mu) * rstd * g4.w + b4.w, 0.f);

    float e2v[8];
    #pragma unroll
    for (int h = 0; h < 8; ++h) e2v[h] = 0.f;
    #pragma unroll
    for (int q = 0; q < 4; ++q) {
        int c = lane * 4 + q;
        const float* wr = w2 + c * 8;
        #pragma unroll
        for (int h = 0; h < 8; ++h) e2v[h] += ya[q] * wr[h];
    }
    #pragma unroll
    for (int off = 1; off < 64; off <<= 1)
        #pragma unroll
        for (int h = 0; h < 8; ++h) e2v[h] += __shfl_xor(e2v[h], off);
    if (lane < 8) ed2g[d * NH + lane] = e2v[lane];
}

// ---------------- batched layer-2 gather (grid y = type) ----------------
__global__ __launch_bounds__(256) void gather_l2_all(const int* __restrict__ row_ptr_g,
                                                     const int* __restrict__ elist_g,
                                                     const float* __restrict__ es_all,
                                                     const float* __restrict__ ed2g_all,
                                                     const unsigned short* __restrict__ hs_all,
                                                     const float* __restrict__ b2,
                                                     const float* __restrict__ gamma,
                                                     const float* __restrict__ beta,
                                                     float* __restrict__ deng_all,
                                                     float* __restrict__ ppart) {
    const int t = blockIdx.y;
    const int* row_ptr = row_ptr_g + t * (N_NODES + 1);
    const int* elist = elist_g + t * N_EDGES;
    const float* es = es_all + (size_t)(6 + t) * N_NODES * NH;
    const float* ed2g = ed2g_all + (size_t)t * N_NODES * NH;
    const unsigned short* hs = hs_all + (size_t)(6 + t) * N_NODES * HC;
    const float* bias = b2 + t * HC;
    const float* gam = gamma + t * HC;
    const float* bet = beta + t * HC;
    float* deng = deng_all + (size_t)t * N_NODES * NH;
    float* psum_part = ppart + (size_t)t * L2_GRID * HC;

    const int tid = threadIdx.x;
    const int lane = tid & 63;
    const int w = tid >> 6;
    const int h_l = lane >> 3;
    const float4 bv = *(const float4*)&bias[lane * 4];
    const float4 g4 = *(const float4*)&gam[lane * 4];
    const float4 b4 = *(const float4*)&bet[lane * 4];

    float4 pool = make_float4(0.f, 0.f, 0.f, 0.f);
    const int base = blockIdx.x * L2_NPB;

    #pragma unroll 1
    for (int rep = 0; rep < L2_NPB / 4; ++rep) {
        const int d = base + rep * 4 + w;
        if (d >= N_NODES) break;

        const float ed_mine = ed2g[d * NH + h_l];
        const int e0 = row_ptr[d], e1n = row_ptr[d + 1];

        float den = 0.f;
        float4 acc = make_float4(0.f, 0.f, 0.f, 0.f);
        for (int i = e0; i < e1n; ++i) {
            int s = elist[i];
            float x = es[s * NH + h_l] + ed_mine;
            x = (x >= 0.f) ? x : 0.2f * x;
            float ex = __expf(x);
            den += ex;
            ushort4_t hv = *(const ushort4_t*)&hs[(size_t)s * HC + lane * 4];
            acc.x += ex * bf2f(hv[0]); acc.y += ex * bf2f(hv[1]);
            acc.z += ex * bf2f(hv[2]); acc.w += ex * bf2f(hv[3]);
        }
        if ((lane & 7) == 0) deng[d * NH + h_l] = den;
        float inv = 1.f / (den + 1e-16f);
        acc.x = acc.x * inv + bv.x; acc.y = acc.y * inv + bv.y;
        acc.z = acc.z * inv + bv.z; acc.w = acc.w * inv + bv.w;

        float s1 = acc.x + acc.y + acc.z + acc.w;
        float s2 = acc.x * acc.x + acc.y * acc.y + acc.z * acc.z + acc.w * acc.w;
        #pragma unroll
        for (int off = 1; off < 64; off <<= 1) { s1 += __shfl_xor(s1, off); s2 += __shfl_xor(s2, off); }
        float mu = s1 * (1.f / 256.f);
        float var = s2 * (1.f / 256.f) - mu * mu;
        float rstd = rsqrtf(var + 1e-5f);
        pool.x += fmaxf((acc.x - mu) * rstd * g4.x + b4.x, 0.f);
        pool.y += fmaxf((acc.y - mu) * rstd * g4.y + b4.y, 0.f);
        pool.z += fmaxf((acc.z - mu) * rstd * g4.z + b4.z, 0.f);
        pool.w += fmaxf((acc.w - mu) * rstd * g4.w + b4.w, 0.f);
    }

    __shared__ float sacc[4][260];
    *(float4*)&sacc[w][lane * 4] = pool;
    __syncthreads();
    float tot = sacc[0][tid] + sacc[1][tid] + sacc[2][tid] + sacc[3][tid];
    psum_part[(size_t)blockIdx.x * HC + tid] = tot;
}

// ---------------- batched pooled-partial reduce ----------------
__global__ __launch_bounds__(256) void pool_reduce_all(const float* __restrict__ ppart,
                                                       float* __restrict__ psums) {
    int t = blockIdx.y;
    const float* part = ppart + (size_t)t * L2_GRID * HC;
    int tid = threadIdx.x;
    float acc = 0.f;
    for (int b = blockIdx.x; b < L2_GRID; b += gridDim.x)
        acc += part[(size_t)b * HC + tid];
    atomicAdd(&psums[t * HC + tid], acc);
}

// ---------------- batched alpha2 writer ----------------
__global__ void alpha_all(const int* __restrict__ ei,
                          const float* __restrict__ es_all,
                          const float* __restrict__ ed2g_all,
                          const float* __restrict__ deng_all,
                          float* __restrict__ out) {
    int t = blockIdx.y;
    int g = blockIdx.x * 256 + threadIdx.x;
    if (g >= N_EDGES * NH) return;
    int e = g >> 3, h = g & 7;
    const int* src = ei + (size_t)t * 2 * N_EDGES;
    const int* dst = src + N_EDGES;
    int s = src[e], d = dst[e];
    const float* es = es_all + (size_t)(6 + t) * N_NODES * NH;
    float x = es[s * NH + h] + ed2g_all[(size_t)t * N_NODES * NH + d * NH + h];
    x = (x >= 0.f) ? x : 0.2f * x;
    out[(size_t)t * N_EDGES * NH + g] =
        __expf(x) / (deng_all[(size_t)t * N_NODES * NH + d * NH + h] + 1e-16f);
}

// ---------------- x_pkg column sums ----------------
__global__ __launch_bounds__(256) void pkg_accum(const float* __restrict__ x, float* __restrict__ sums) {
    int tid = threadIdx.x;
    int col = tid & 127;
    int rof = tid >> 7;
    float acc = 0.f;
    for (int r = blockIdx.x * 2 + rof; r < N_NODES; r += gridDim.x * 2)
        acc += x[(size_t)r * D_IN + col];
    atomicAdd(&sums[col], acc);
}

// ---------------- final classifier dot ----------------
__global__ __launch_bounds__(256) void logits_k(const float* __restrict__ psums,
                                                const float* __restrict__ ksums,
                                                const float* __restrict__ Wc,
                                                const float* __restrict__ bc,
                                                float* __restrict__ out) {
    int tid = threadIdx.x;
    const float inv = 1.f / (float)N_NODES;
    float acc = 0.f;
    for (int i = tid; i < N_TYPES * HC; i += 256) acc += psums[i] * inv * Wc[i];
    if (tid < D_IN) acc += ksums[tid] * inv * Wc[N_TYPES * HC + tid];
    #pragma unroll
    for (int off = 32; off; off >>= 1) acc += __shfl_down(acc, off);
    __shared__ float w[4];
    if ((tid & 63) == 0) w[tid >> 6] = acc;
    __syncthreads();
    if (tid == 0) out[0] = w[0] + w[1] + w[2] + w[3] + bc[0];
}

static inline void zf(float* p, int n, hipStream_t stream) {
    int n4 = (n + 3) >> 2;
    zero4<<<(n4 + 255) / 256, 256, 0, stream>>>((float4*)p, n4);
}

extern "C" void kernel_launch(void* const* d_in, const int* in_sizes, int n_in,
                              void* d_out, int out_size, void* d_ws, size_t ws_size,
                              hipStream_t stream) {
    const float* x_pkg    = (const float*)d_in[0];
    const float* x_tgt    = (const float*)d_in[1];
    const int*   ei       = (const int*)d_in[2];
    const float* W1_src   = (const float*)d_in[3];
    const float* W1_dst   = (const float*)d_in[4];
    const float* att1_src = (const float*)d_in[5];
    const float* att1_dst = (const float*)d_in[6];
    const float* b1       = (const float*)d_in[7];
    const float* W2_src   = (const float*)d_in[8];
    const float* W2_dst   = (const float*)d_in[9];
    const float* att2_src = (const float*)d_in[10];
    const float* att2_dst = (const float*)d_in[11];
    const float* b2       = (const float*)d_in[12];
    const float* gamma    = (const float*)d_in[13];
    const float* beta     = (const float*)d_in[14];
    const float* Wc       = (const float*)d_in[15];
    const float* bc       = (const float*)d_in[16];
    float* out = (float*)d_out;

    // ---- workspace layout (~225 MB of the ~369 MB ws) ----
    char* wsb = (char*)d_ws;
    unsigned short* xpkg_bf = (unsigned short*)wsb;                    // 30000*128
    unsigned short* hs_all  = xpkg_bf + (size_t)N_NODES * D_IN;        // 12*30000*256
    float* es_all   = (float*)(hs_all + (size_t)12 * N_NODES * HC);    // 12*30000*8
    float* ed2g_all = es_all + (size_t)12 * N_NODES * NH;              // 6*30000*8
    float* deng_all = ed2g_all + (size_t)N_TYPES * N_NODES * NH;       // 6*30000*8
    float* psums    = deng_all + (size_t)N_TYPES * N_NODES * NH;       // 1536
    float* ksums    = psums + N_TYPES * HC;                            // 128
    float* wd1      = ksums + D_IN;                                    // 6*128*8
    float* wd2      = wd1 + N_TYPES * D_IN * NH;                       // 6*256*8
    float* ppart    = wd2 + N_TYPES * HC * NH;                         // 6*L2_GRID*256
    int* counts  = (int*)(ppart + (size_t)N_TYPES * L2_GRID * HC);     // 6*30000
    int* row_ptr = counts + N_TYPES * N_NODES;                         // 6*30001
    int* cursor  = row_ptr + N_TYPES * (N_NODES + 1);                  // 6*30000
    int* elist   = cursor + N_TYPES * N_NODES;                         // 6*100000

    dim3 egrid((N_EDGES + 255) / 256, N_TYPES);

    // ---- setup (independent small kernels) ----
    zf(psums, N_TYPES * HC, stream);
    zf(ksums, D_IN, stream);
    pkg_accum<<<256, 256, 0, stream>>>(x_pkg, ksums);
    {
        int tot = N_TYPES * (D_IN + HC) * NH;
        att_weight_all<<<(tot + 255) / 256, 256, 0, stream>>>(W1_dst, att1_dst, W2_dst, att2_dst, wd1, wd2);
    }
    to_bf16<<<((N_NODES * D_IN / 4) + 255) / 256, 256, 0, stream>>>(x_pkg, xpkg_bf, N_NODES * D_IN / 4);
    zero_i<<<(N_TYPES * N_NODES + 255) / 256, 256, 0, stream>>>(counts, N_TYPES * N_NODES);
    hist_all<<<egrid, 256, 0, stream>>>(ei, counts);
    scan_all<<<N_TYPES, SCAN_T, 0, stream>>>(counts, row_ptr, cursor);
    fill_all<<<egrid, 256, 0, stream>>>(ei, cursor, elist);

    // ---- one fat GEMM: all 12 src-side projections ----
    {
        dim3 g((N_NODES + 63) / 64, HC / 64, 12);
        gemm_all<<<g, 256, 0, stream>>>(xpkg_bf, W1_src, W2_src, att1_src, att2_src,
                                        hs_all, es_all);
    }

    // ---- batched layer 1 ----
    {
        dim3 g(N_NODES / 4, N_TYPES);
        gather_l1_all<<<g, 256, 0, stream>>>(row_ptr, elist, es_all, x_tgt, wd1, hs_all,
                                             b1, gamma, beta, wd2, ed2g_all);
    }

    // ---- batched layer 2 ----
    {
        dim3 g(L2_GRID, N_TYPES);
        gather_l2_all<<<g, 256, 0, stream>>>(row_ptr, elist, es_all, ed2g_all, hs_all,
                                             b2, gamma, beta, deng_all, ppart);
    }
    {
        dim3 g(8, N_TYPES);
        pool_reduce_all<<<g, 256, 0, stream>>>(ppart, psums);
    }
    {
        dim3 g((N_EDGES * NH + 255) / 256, N_TYPES);
        alpha_all<<<g, 256, 0, stream>>>(ei, es_all, ed2g_all, deng_all, out + 1);
    }

    logits_k<<<1, 256, 0, stream>>>(psums, ksums, Wc, bc, out);
}